// Round 10
// baseline (442.999 us; speedup 1.0000x reference)
//
#include <hip/hip_runtime.h>
#include <hip/hip_cooperative_groups.h>

namespace cg = cooperative_groups;

#define EPS 1e-5f
#define SLOPE 0.01f

typedef __attribute__((ext_vector_type(4))) float f32x4;
typedef __attribute__((ext_vector_type(8))) short bf16x8;

__device__ __forceinline__ short f2bf(float f) {
    unsigned u = __float_as_uint(f);
    unsigned r = (u + 0x7FFFu + ((u >> 16) & 1u)) >> 16;
    return (short)r;
}
__device__ __forceinline__ float lrelu(float v) { return v >= 0.f ? v : SLOPE * v; }

__device__ __forceinline__ void gload16(const float* g, float* l) {
    __builtin_amdgcn_global_load_lds(
        (const __attribute__((address_space(1))) unsigned*)g,
        (__attribute__((address_space(3))) unsigned*)l, 16, 0, 0);
}
__device__ __forceinline__ void gload4(const float* g, float* l) {
    __builtin_amdgcn_global_load_lds(
        (const __attribute__((address_space(1))) unsigned*)g,
        (__attribute__((address_space(3))) unsigned*)l, 4, 0, 0);
}

#define WCASE(N) case N: asm volatile("s_waitcnt vmcnt(" #N ")" ::: "memory"); break;
__device__ __forceinline__ void wait_vm(int n) {
    switch (n) {
    WCASE(0) WCASE(1) WCASE(2) WCASE(3) WCASE(4) WCASE(5) WCASE(6) WCASE(7)
    WCASE(8) WCASE(9) WCASE(10) WCASE(11) WCASE(12) WCASE(13) WCASE(14) WCASE(15)
    WCASE(16) WCASE(17) WCASE(18) WCASE(19) WCASE(20) WCASE(21) WCASE(22) WCASE(23)
    WCASE(24) WCASE(25) WCASE(26) WCASE(27) WCASE(28) WCASE(29) WCASE(30) WCASE(31)
    WCASE(32) WCASE(33) WCASE(34) WCASE(35) WCASE(36) WCASE(37) WCASE(38) WCASE(39)
    WCASE(40) WCASE(41) WCASE(42) WCASE(43) WCASE(44) WCASE(45) WCASE(46) WCASE(47)
    WCASE(48) WCASE(49) WCASE(50) WCASE(51) WCASE(52) WCASE(53) WCASE(54) WCASE(55)
    WCASE(56) WCASE(57) WCASE(58) WCASE(59) WCASE(60) WCASE(61) WCASE(62) WCASE(63)
    default: asm volatile("s_waitcnt vmcnt(0)" ::: "memory"); break;
    }
}

// pair-level swizzle: stored 16B slot s of row r holds source slot
// ((s>>1 ^ r)&7)*2 | (s&1). Read of source pair p0 -> stored pair p0^(r&7).
__device__ __forceinline__ int swz_cf(int s, int r) {
    return ((((s >> 1) ^ r) & 7) << 1) | (s & 1);
}

// ---------------------------------------------------------------------------
// One 16-row tile of one stage (R9-proven body). Per-wave private LDS
// staging, 2-deep DMA pipeline, EXACT vmcnt windows (all younger VMEM ops
// counted; in-order retire). BMODE: 0 = B inline at MFMA; 1 = B triple-
// buffered (loadB(c+2) after the wait); 2 = B fully preloaded INSIDE this
// function (compile-time indexed -> VGPR-resident; never pointer-passed).
// ---------------------------------------------------------------------------
template<int XD, int SD, int NCX, int NCS, int NT, int NVALID, int OD,
         bool XA16, int XCLAMP, bool BN, bool STATS, int BMODE>
__device__ __forceinline__ void run_tile(
    const float* __restrict__ xsrc, const float* __restrict__ skip,
    const int* __restrict__ idx, const short* __restrict__ wtf,
    const float* __restrict__ bias, const float* bnl,
    float* __restrict__ out, float* lstats, float* awave,
    int tile, int lane)
{
    constexpr int NC = NCX + NCS;
    const int lr = lane & 15;
    const int kg = lane >> 4;
    const int row0w = tile * 16;

    auto sD = [](int c) -> int {
        if (c < 0 || c >= NC) return 0;
        return (c < NCX && !XA16) ? 16 : 4;
    };
    auto sB = [](int c) -> int {
        if (c < 0 || c >= NC) return 0;
        return 2 * NT;
    };

    const float* prow[XA16 ? 4 : 16];
    if constexpr (XA16) {
#pragma unroll
        for (int q = 0; q < 4; ++q)
            prow[q] = xsrc + (size_t)idx[row0w + q * 4 + kg] * XD;
    } else {
#pragma unroll
        for (int j = 0; j < 16; ++j)
            prow[j] = xsrc + (size_t)idx[row0w + j] * XD;
    }

    auto issue = [&](int c) {
        float* wb = awave + (c % 3) * 1024;
        if (c < NCX) {
            if constexpr (XA16) {
#pragma unroll
                for (int q = 0; q < 4; ++q) {
                    const int rl = q * 4 + kg;
                    const int cf = swz_cf(lane & 15, rl);
                    gload16(prow[q] + c * 64 + cf * 4, wb + q * 256);
                }
            } else {
#pragma unroll
                for (int j = 0; j < 16; ++j) {
                    const int cf = swz_cf(lane >> 2, j);
                    int col = c * 64 + cf * 4 + (lane & 3);
                    if (XCLAMP > 0 && c == NCX - 1) col = min(col, XCLAMP - 1);
                    gload4(prow[j] + col, wb + j * 64);
                }
            }
        } else {
            const int jc = c - NCX;
#pragma unroll
            for (int q = 0; q < 4; ++q) {
                const int rl = q * 4 + kg;
                const int cf = swz_cf(lane & 15, rl);
                gload16(skip + (size_t)(row0w + rl) * SD + jc * 64 + cf * 4,
                        wb + q * 256);
            }
        }
    };

    bf16x8 Bp[(BMODE == 2) ? 2 * NC * NT : 1];
    bf16x8 Bf[(BMODE == 1) ? 3 : 1][2][NT];
    auto loadB = [&](int cc) {
#pragma unroll
        for (int tt = 0; tt < 2; ++tt)
#pragma unroll
            for (int nt = 0; nt < NT; ++nt)
                Bf[cc % 3][tt][nt] =
                    *(const bf16x8*)(wtf + (((2 * cc + tt) * NT + nt) << 9));
    };

    f32x4 acc[NT];
#pragma unroll
    for (int nt = 0; nt < NT; ++nt) acc[nt] = (f32x4){0.f, 0.f, 0.f, 0.f};

    if constexpr (BMODE == 2) {   // preload all B BEFORE any DMA (stays older)
#pragma unroll
        for (int tv = 0; tv < 2 * NC; ++tv)
#pragma unroll
            for (int nt = 0; nt < NT; ++nt)
                Bp[tv * NT + nt] = *(const bf16x8*)(wtf + ((tv * NT + nt) << 9));
    }

    issue(0);
    if constexpr (BMODE == 1) loadB(0);
    if (NC > 1) issue(1);
    if constexpr (BMODE == 1) { if (NC > 1) loadB(1); }

#pragma unroll
    for (int c = 0; c < NC; ++c) {
        if (c + 2 < NC) issue(c + 2);
        int w;
        if constexpr (BMODE == 0)      w = sD(c+1) + sD(c+2) + sB(c-1) + sB(c-2);
        else if constexpr (BMODE == 1) w = sD(c+1) + sD(c+2) + sB(c) + sB(c+1);
        else                           w = sD(c+1) + sD(c+2);
        wait_vm(w > 63 ? 63 : w);
        if constexpr (BMODE == 1) { if (c + 2 < NC) loadB(c + 2); }

        const float* wb = awave + (c % 3) * 1024;
#pragma unroll
        for (int tt = 0; tt < 2; ++tt) {
            const int p0 = tt * 4 + kg;
            const float* fp = wb + lr * 64 + ((p0 ^ (lr & 7)) << 3);
            f32x4 lo = *(const f32x4*)fp;
            f32x4 hi = *(const f32x4*)(fp + 4);
            float v[8];
#pragma unroll
            for (int e = 0; e < 4; ++e) { v[e] = lo[e]; v[e + 4] = hi[e]; }
            if (BN && c < NCX) {
                const int kb = c * 64 + tt * 32 + kg * 8;
                f32x4 c0 = *(const f32x4*)&bnl[kb];
                f32x4 c1 = *(const f32x4*)&bnl[kb + 4];
                f32x4 h0 = *(const f32x4*)&bnl[NCX * 64 + kb];
                f32x4 h1 = *(const f32x4*)&bnl[NCX * 64 + kb + 4];
#pragma unroll
                for (int e = 0; e < 4; ++e) {
                    v[e]     = lrelu(fmaf(v[e],     c0[e], h0[e]));
                    v[e + 4] = lrelu(fmaf(v[e + 4], c1[e], h1[e]));
                }
            }
            bf16x8 a;
#pragma unroll
            for (int e = 0; e < 8; ++e) a[e] = f2bf(v[e]);
#pragma unroll
            for (int nt = 0; nt < NT; ++nt) {
                bf16x8 b;
                if constexpr (BMODE == 2)      b = Bp[(2 * c + tt) * NT + nt];
                else if constexpr (BMODE == 1) b = Bf[c % 3][tt][nt];
                else b = *(const bf16x8*)(wtf + (((2 * c + tt) * NT + nt) << 9));
                acc[nt] = __builtin_amdgcn_mfma_f32_16x16x32_bf16(a, b, acc[nt], 0, 0, 0);
            }
        }
    }

    // bias + store
#pragma unroll
    for (int nt = 0; nt < NT; ++nt) {
        const int n = nt * 16 + lr;
        const float bv = (n < NVALID) ? bias[n] : 0.f;
#pragma unroll
        for (int r = 0; r < 4; ++r) acc[nt][r] += bv;
        if (n < NVALID) {
#pragma unroll
            for (int r = 0; r < 4; ++r)
                out[(size_t)(row0w + kg * 4 + r) * OD + n] = acc[nt][r];
        }
    }

    if constexpr (STATS) {
#pragma unroll
        for (int nt = 0; nt < NT; ++nt) {
            float s = acc[nt][0] + acc[nt][1] + acc[nt][2] + acc[nt][3];
            float q = acc[nt][0]*acc[nt][0] + acc[nt][1]*acc[nt][1]
                    + acc[nt][2]*acc[nt][2] + acc[nt][3]*acc[nt][3];
            s += __shfl_xor(s, 16, 64);
            s += __shfl_xor(s, 32, 64);
            q += __shfl_xor(q, 16, 64);
            q += __shfl_xor(q, 32, 64);
            if (lane < 16) {
                atomicAdd(&lstats[nt * 16 + lr], s);
                atomicAdd(&lstats[NT * 16 + nt * 16 + lr], q);
            }
        }
    }
}

// ---------------------------------------------------------------------------
// Single cooperative kernel: prep -> sync -> stage1 -> sync -> stage2 -> sync
// -> stage3, BN finalized per-block into LDS after each sync.
// ---------------------------------------------------------------------------
__global__ __launch_bounds__(256, 3)
void fused_decoder(const float* __restrict__ feats, const float* __restrict__ skip1,
                   const float* __restrict__ skip2, const float* __restrict__ skip3,
                   const int* __restrict__ idx1, const int* __restrict__ idx2,
                   const int* __restrict__ idx3,
                   const float* __restrict__ W1, const float* __restrict__ W2,
                   const float* __restrict__ W3,
                   const float* __restrict__ b1, const float* __restrict__ g1,
                   const float* __restrict__ be1,
                   const float* __restrict__ b2, const float* __restrict__ g2,
                   const float* __restrict__ be2,
                   const float* __restrict__ b3,
                   float* __restrict__ ws, float* __restrict__ outp)
{
    __shared__ __align__(16) float abuf[4][3][1024];   // 48 KB
    __shared__ __align__(16) float bnl[384];
    __shared__ float lstats[288];

    float* sum1 = ws;        float* sq1 = ws + 256;
    float* sum2 = ws + 512;  float* sq2 = ws + 768;
    short* Wt1 = (short*)(ws + 2048);        // 26*9*512 = 119808
    short* Wt2 = Wt1 + 119808;               // 14*4*512 = 28672
    short* Wt3 = Wt2 + 28672;                // 6*3*512  = 9216
    float* y1  = ws + 80896;                 // [16384][192]
    float* y2  = y1 + 16384 * 192;           // [65536][64]

    const int tid = threadIdx.x;
    const int wave = tid >> 6, lane = tid & 63;
    const int gw = blockIdx.x * 4 + wave;
    const int nw = gridDim.x * 4;
    float* awave = &abuf[wave][0][0];
    cg::grid_group gg = cg::this_grid();

    // ---- phase 0: prep (stats zero, fragment-ordered Wt, y1 pad zero) ----
    {
        const int id0 = blockIdx.x * 256 + tid;
        const int str = gridDim.x * 256;
        for (int id = id0; id < 2048; id += str) ws[id] = 0.f;
        for (int id = id0; id < 26 * 9 * 512; id += str) {
            int e = id & 7, ln = (id >> 3) & 63, g = id >> 9;
            int t = g / 9, nt = g - t * 9;
            int kv = t * 32 + (ln >> 4) * 8 + e;
            int n  = nt * 16 + (ln & 15);
            float v = 0.f; int ks = -1;
            if (kv < 258) ks = kv; else if (kv >= 320) ks = kv - 62;
            if (ks >= 0 && ks < 770 && n < 129) v = W1[ks * 129 + n];
            Wt1[id] = f2bf(v);
        }
        for (int id = id0; id < 14 * 4 * 512; id += str) {
            int e = id & 7, ln = (id >> 3) & 63, g = id >> 9;
            int t = g >> 2, nt = g & 3;
            int kv = t * 32 + (ln >> 4) * 8 + e;
            int n  = nt * 16 + (ln & 15);
            float v = 0.f; int ks = -1;
            if (kv < 129) ks = kv; else if (kv >= 192) ks = kv - 63;
            if (ks >= 0 && ks < 385) v = W2[ks * 64 + n];
            Wt2[id] = f2bf(v);
        }
        for (int id = id0; id < 6 * 3 * 512; id += str) {
            int e = id & 7, ln = (id >> 3) & 63, g = id >> 9;
            int t = g / 3, nt = g - t * 3;
            int kv = t * 32 + (ln >> 4) * 8 + e;
            int n  = nt * 16 + (ln & 15);
            float v = (n < 34) ? W3[kv * 34 + n] : 0.f;
            Wt3[id] = f2bf(v);
        }
        for (int id = id0; id < 16384 * 64; id += str) {
            int r = id >> 6, c = id & 63;
            y1[(size_t)r * 192 + 128 + c] = 0.f;
        }
    }
    __threadfence();
    gg.sync();

    for (int i = tid; i < 288; i += 256) lstats[i] = 0.f;
    __syncthreads();

    // ---- stage 1: 1024 tiles ----
    for (int t = gw; t < 1024; t += nw)
        run_tile<258, 512, 5, 8, 9, 129, 192, false, 258, false, true, 0>(
            feats, skip3, idx1, Wt1 + (lane << 3), b1, nullptr,
            y1, lstats, awave, t, lane);
    __syncthreads();
    for (int i = tid; i < 144; i += 256) {
        atomicAdd(&sum1[i], lstats[i]);
        atomicAdd(&sq1[i], lstats[144 + i]);
    }
    __threadfence();
    gg.sync();

    // BN1 finalize (192 ch incl. zero pads) + re-zero lstats
    for (int i = tid; i < 192; i += 256) {
        float sc = 0.f, sh = 0.f;
        if (i < 129) {
            float m   = sum1[i] * (1.f / 16384.f);
            float var = fmaf(-m, m, sq1[i] * (1.f / 16384.f));
            sc = rsqrtf(var + EPS) * g1[i];
            sh = fmaf(-m, sc, be1[i]);
        }
        bnl[i] = sc;
        bnl[192 + i] = sh;
    }
    for (int i = tid; i < 288; i += 256) lstats[i] = 0.f;
    __syncthreads();

    // ---- stage 2: 4096 tiles ----
    for (int t = gw; t < 4096; t += nw)
        run_tile<192, 256, 3, 4, 4, 64, 64, true, 0, true, true, 1>(
            y1, skip2, idx2, Wt2 + (lane << 3), b2, bnl,
            y2, lstats, awave, t, lane);
    __syncthreads();
    for (int i = tid; i < 64; i += 256) {
        atomicAdd(&sum2[i], lstats[i]);
        atomicAdd(&sq2[i], lstats[64 + i]);
    }
    __threadfence();
    gg.sync();

    // BN2 finalize (64 ch)
    for (int i = tid; i < 64; i += 256) {
        float m   = sum2[i] * (1.f / 65536.f);
        float var = fmaf(-m, m, sq2[i] * (1.f / 65536.f));
        float sc = rsqrtf(var + EPS) * g2[i];
        bnl[i] = sc;
        bnl[64 + i] = fmaf(-m, sc, be2[i]);
    }
    __syncthreads();

    // ---- stage 3: 16384 tiles ----
    for (int t = gw; t < 16384; t += nw)
        run_tile<64, 128, 1, 2, 3, 34, 34, true, 0, true, false, 2>(
            y2, skip1, idx3, Wt3 + (lane << 3), b3, bnl,
            outp, nullptr, awave, t, lane);
}

extern "C" void kernel_launch(void* const* d_in, const int* in_sizes, int n_in,
                              void* d_out, int out_size, void* d_ws, size_t ws_size,
                              hipStream_t stream) {
    const float* feats = (const float*)d_in[0];
    const float* skip1 = (const float*)d_in[1];
    const float* skip2 = (const float*)d_in[2];
    const float* skip3 = (const float*)d_in[3];
    const int*   idx1  = (const int*)d_in[4];
    const int*   idx2  = (const int*)d_in[5];
    const int*   idx3  = (const int*)d_in[6];
    const float* W1    = (const float*)d_in[7];
    const float* b1    = (const float*)d_in[8];
    const float* g1    = (const float*)d_in[9];
    const float* be1   = (const float*)d_in[10];
    const float* W2    = (const float*)d_in[11];
    const float* b2    = (const float*)d_in[12];
    const float* g2    = (const float*)d_in[13];
    const float* be2   = (const float*)d_in[14];
    const float* W3    = (const float*)d_in[15];
    const float* b3    = (const float*)d_in[16];

    float* ws   = (float*)d_ws;
    float* outp = (float*)d_out;

    int maxb = 0;
    hipError_t e = hipOccupancyMaxActiveBlocksPerMultiprocessor(
        &maxb, reinterpret_cast<const void*>(fused_decoder), 256, 0);
    if (e != hipSuccess || maxb < 1) maxb = 2;
    if (maxb > 3) maxb = 3;
    int ncu = 256;
    hipDeviceProp_t props;
    if (hipGetDeviceProperties(&props, 0) == hipSuccess && props.multiProcessorCount > 0)
        ncu = props.multiProcessorCount;

    void* args[] = {
        (void*)&feats, (void*)&skip1, (void*)&skip2, (void*)&skip3,
        (void*)&idx1, (void*)&idx2, (void*)&idx3,
        (void*)&W1, (void*)&W2, (void*)&W3,
        (void*)&b1, (void*)&g1, (void*)&be1,
        (void*)&b2, (void*)&g2, (void*)&be2,
        (void*)&b3, (void*)&ws, (void*)&outp
    };
    hipLaunchCooperativeKernel(reinterpret_cast<const void*>(fused_decoder),
                               dim3(ncu * maxb), dim3(256), args, 0, stream);
}

// Round 11
// 103.588 us; speedup vs baseline: 4.2766x; 4.2766x over previous
//
#include <hip/hip_runtime.h>

#define EPS 1e-5f
#define SLOPE 0.01f

typedef __attribute__((ext_vector_type(4))) float f32x4;
typedef __attribute__((ext_vector_type(8))) short bf16x8;

__device__ __forceinline__ short f2bf(float f) {
    unsigned u = __float_as_uint(f);
    unsigned r = (u + 0x7FFFu + ((u >> 16) & 1u)) >> 16;
    return (short)r;
}
__device__ __forceinline__ float bf2f(short h) {
    return __uint_as_float(((unsigned)(unsigned short)h) << 16);
}
__device__ __forceinline__ float lrelu(float v) { return v >= 0.f ? v : SLOPE * v; }

__device__ __forceinline__ void gload16(const void* g, float* l) {
    __builtin_amdgcn_global_load_lds(
        (const __attribute__((address_space(1))) unsigned*)g,
        (__attribute__((address_space(3))) unsigned*)l, 16, 0, 0);
}
__device__ __forceinline__ void gload4(const void* g, float* l) {
    __builtin_amdgcn_global_load_lds(
        (const __attribute__((address_space(1))) unsigned*)g,
        (__attribute__((address_space(3))) unsigned*)l, 4, 0, 0);
}

#define WCASE(N) case N: asm volatile("s_waitcnt vmcnt(" #N ")" ::: "memory"); break;
__device__ __forceinline__ void wait_vm(int n) {
    switch (n) {
    WCASE(0) WCASE(1) WCASE(2) WCASE(3) WCASE(4) WCASE(5) WCASE(6) WCASE(7)
    WCASE(8) WCASE(9) WCASE(10) WCASE(11) WCASE(12) WCASE(13) WCASE(14) WCASE(15)
    WCASE(16) WCASE(17) WCASE(18) WCASE(19) WCASE(20) WCASE(21) WCASE(22) WCASE(23)
    WCASE(24) WCASE(25) WCASE(26) WCASE(27) WCASE(28) WCASE(29) WCASE(30) WCASE(31)
    WCASE(32) WCASE(33) WCASE(34) WCASE(35) WCASE(36) WCASE(37) WCASE(38) WCASE(39)
    WCASE(40) WCASE(41) WCASE(42) WCASE(43) WCASE(44) WCASE(45) WCASE(46) WCASE(47)
    WCASE(48) WCASE(49) WCASE(50) WCASE(51) WCASE(52) WCASE(53) WCASE(54) WCASE(55)
    WCASE(56) WCASE(57) WCASE(58) WCASE(59) WCASE(60) WCASE(61) WCASE(62) WCASE(63)
    default: asm volatile("s_waitcnt vmcnt(0)" ::: "memory"); break;
    }
}

// f32-region pair-level swizzle (R9-proven)
__device__ __forceinline__ int swz_cf(int s, int r) {
    return ((((s >> 1) ^ r) & 7) << 1) | (s & 1);
}

// ---------------------------------------------------------------------------
// prep: fragment-ordered Wt (Wt[((tv*NT+nt)*64+lane)*8+e] = W[kv][n] bf16),
// zero 4096-float stats block, zero y1 bf16 pad columns 128..191.
//  S1 (26 tiles, NT=9): kv<258 -> W1 row kv; 258..319 -> 0; >=320 -> kv-62
//  S2 (14 tiles, NT=4): kv<129 -> W2 row kv; 129..191 -> 0; >=192 -> kv-63
//  S3 ( 6 tiles, NT=3): kv -> W3 row kv (exact)
// ---------------------------------------------------------------------------
__global__ void prep(const float* __restrict__ W1, const float* __restrict__ W2,
                     const float* __restrict__ W3,
                     short* __restrict__ Wt1, short* __restrict__ Wt2,
                     short* __restrict__ Wt3, float* __restrict__ stats,
                     short* __restrict__ y1h)
{
    const int id0 = blockIdx.x * 256 + threadIdx.x;
    const int str = gridDim.x * 256;
    for (int id = id0; id < 4096; id += str) stats[id] = 0.f;
    for (int id = id0; id < 26 * 9 * 512; id += str) {
        int e = id & 7, ln = (id >> 3) & 63, g = id >> 9;
        int t = g / 9, nt = g - t * 9;
        int kv = t * 32 + (ln >> 4) * 8 + e;
        int n  = nt * 16 + (ln & 15);
        float v = 0.f; int ks = -1;
        if (kv < 258) ks = kv; else if (kv >= 320) ks = kv - 62;
        if (ks >= 0 && ks < 770 && n < 129) v = W1[ks * 129 + n];
        Wt1[id] = f2bf(v);
    }
    for (int id = id0; id < 14 * 4 * 512; id += str) {
        int e = id & 7, ln = (id >> 3) & 63, g = id >> 9;
        int t = g >> 2, nt = g & 3;
        int kv = t * 32 + (ln >> 4) * 8 + e;
        int n  = nt * 16 + (ln & 15);
        float v = 0.f; int ks = -1;
        if (kv < 129) ks = kv; else if (kv >= 192) ks = kv - 63;
        if (ks >= 0 && ks < 385) v = W2[ks * 64 + n];
        Wt2[id] = f2bf(v);
    }
    for (int id = id0; id < 6 * 3 * 512; id += str) {
        int e = id & 7, ln = (id >> 3) & 63, g = id >> 9;
        int t = g / 3, nt = g - t * 3;
        int kv = t * 32 + (ln >> 4) * 8 + e;
        int n  = nt * 16 + (ln & 15);
        float v = (n < 34) ? W3[kv * 34 + n] : 0.f;
        Wt3[id] = f2bf(v);
    }
    for (int id = id0; id < 16384 * 64; id += str)
        y1h[(size_t)(id >> 6) * 192 + 128 + (id & 63)] = 0;
}

// ---------------------------------------------------------------------------
// MFMA stage (R9-proven scheduling). XMODE: 0 = x is f32 rows via gload4
// (clamped), 2 = x is bf16 rows (gathered), staged 2 instrs/chunk with 8-slot
// XOR swizzle (slot_st = slot_src ^ (row&7), conflict-free). Skip region is
// always f32 gload16 + pair swizzle. BMODE: 0 = B inline; 1 = B triple-
// buffered; 2 = B fully preloaded before any DMA. Stats: 8-way-split global
// atomics (part = blockIdx&7). BN finalize in-kernel from 8 partials.
// OUTBF: store output as bf16 shorts (y1/y2) vs f32 (final).
// ---------------------------------------------------------------------------
template<int XD, int SD, int NCX, int NCS, int NT, int NVALID, int ODe,
         int XMODE, int XCLAMP, int BNC, int BNSTR, bool STATS, int BMODE, int MINW,
         bool OUTBF>
__global__ __launch_bounds__(256, MINW)
void mfma_stage(const void* __restrict__ xsrcv, const float* __restrict__ skip,
                const int* __restrict__ idx, const short* __restrict__ Wt,
                const float* __restrict__ bias,
                const float* __restrict__ bnsum, const float* __restrict__ bnsq,
                const float* __restrict__ bng, const float* __restrict__ bnbe,
                float invN, void* __restrict__ outv,
                float* __restrict__ ssum, float* __restrict__ ssq)
{
    constexpr int NC = NCX + NCS;
    constexpr bool BN = (BNC > 0);
    constexpr int NPAD = NT * 16;

    __shared__ __align__(16) float abuf[4][3][1024];              // 48 KB
    __shared__ __align__(16) float bnl[BN ? 2 * NCX * 64 : 4];

    const int tid  = threadIdx.x;
    const int wave = tid >> 6, lane = tid & 63;
    const int lr = lane & 15;
    const int kg = lane >> 4;
    const int row0w = (blockIdx.x * 4 + wave) * 16;
    const short* wtf = Wt + (lane << 3);
    float* awave = &abuf[wave][0][0];

    if (BN) {   // finalize BN from 8-way-split global stats
        for (int i = tid; i < NCX * 64; i += 256) {
            float sc = 0.f, sh = 0.f;
            if (i < BNC) {
                float s = 0.f, q = 0.f;
#pragma unroll
                for (int p = 0; p < 8; ++p) {
                    s += bnsum[p * BNSTR + i];
                    q += bnsq[p * BNSTR + i];
                }
                float m   = s * invN;
                float var = fmaf(-m, m, q * invN);
                float rs  = rsqrtf(var + EPS);
                sc = rs * bng[i];
                sh = fmaf(-m, sc, bnbe[i]);
            }
            bnl[i] = sc;
            bnl[NCX * 64 + i] = sh;
        }
        __syncthreads();
    }

    // gathered-row pointers
    const float* prowf[XMODE == 0 ? 16 : 1];
    const short* prowh[XMODE == 2 ? 2 : 1];
    if constexpr (XMODE == 0) {
#pragma unroll
        for (int j = 0; j < 16; ++j)
            prowf[j] = (const float*)xsrcv + (size_t)idx[row0w + j] * XD;
    } else {
#pragma unroll
        for (int i = 0; i < 2; ++i)
            prowh[i] = (const short*)xsrcv
                       + (size_t)idx[row0w + i * 8 + (lane >> 3)] * XD;
    }

    auto sD = [](int c) -> int {
        if (c < 0 || c >= NC) return 0;
        if (c < NCX) return (XMODE == 0) ? 16 : 2;
        return 4;
    };
    auto sB = [](int c) -> int {
        if (c < 0 || c >= NC) return 0;
        return 2 * NT;
    };

    auto issue = [&](int c) {
        float* wb = awave + (c % 3) * 1024;
        if (c < NCX) {
            if constexpr (XMODE == 2) {
#pragma unroll
                for (int i = 0; i < 2; ++i) {
                    const int r  = i * 8 + (lane >> 3);
                    const int ss = (lane & 7) ^ (r & 7);
                    gload16(prowh[i] + c * 64 + ss * 8, wb + i * 256);
                }
            } else {
#pragma unroll
                for (int j = 0; j < 16; ++j) {
                    const int cf = swz_cf(lane >> 2, j);
                    int col = c * 64 + cf * 4 + (lane & 3);
                    if (XCLAMP > 0 && c == NCX - 1) col = min(col, XCLAMP - 1);
                    gload4(prowf[j] + col, wb + j * 64);
                }
            }
        } else {
            const int jc = c - NCX;
#pragma unroll
            for (int q = 0; q < 4; ++q) {
                const int rl = q * 4 + kg;
                const int cf = swz_cf(lane & 15, rl);
                gload16(skip + (size_t)(row0w + rl) * SD + jc * 64 + cf * 4,
                        wb + q * 256);
            }
        }
    };

    bf16x8 Bp[(BMODE == 2) ? 2 * NC * NT : 1];
    bf16x8 Bf[(BMODE == 1) ? 3 : 1][2][NT];
    auto loadB = [&](int cc) {
#pragma unroll
        for (int tt = 0; tt < 2; ++tt)
#pragma unroll
            for (int nt = 0; nt < NT; ++nt)
                Bf[cc % 3][tt][nt] =
                    *(const bf16x8*)(wtf + (((2 * cc + tt) * NT + nt) << 9));
    };

    f32x4 acc[NT];
#pragma unroll
    for (int nt = 0; nt < NT; ++nt) acc[nt] = (f32x4){0.f, 0.f, 0.f, 0.f};

    if constexpr (BMODE == 2) {   // all B loaded BEFORE any DMA (stays older)
#pragma unroll
        for (int tv = 0; tv < 2 * NC; ++tv)
#pragma unroll
            for (int nt = 0; nt < NT; ++nt)
                Bp[tv * NT + nt] = *(const bf16x8*)(wtf + ((tv * NT + nt) << 9));
    }

    issue(0);
    if constexpr (BMODE == 1) loadB(0);
    if (NC > 1) issue(1);
    if constexpr (BMODE == 1) { if (NC > 1) loadB(1); }

#pragma unroll
    for (int c = 0; c < NC; ++c) {
        if (c + 2 < NC) issue(c + 2);
        int w;
        if constexpr (BMODE == 0)      w = sD(c+1) + sD(c+2) + sB(c-1) + sB(c-2);
        else if constexpr (BMODE == 1) w = sD(c+1) + sD(c+2) + sB(c) + sB(c+1);
        else                           w = sD(c+1) + sD(c+2);
        wait_vm(w > 63 ? 63 : w);
        if constexpr (BMODE == 1) { if (c + 2 < NC) loadB(c + 2); }

        const float* wb = awave + (c % 3) * 1024;
#pragma unroll
        for (int tt = 0; tt < 2; ++tt) {
            bf16x8 a;
            if (c < NCX && XMODE == 2) {
                // bf16 x fragment: direct bf16x8 read, conflict-free XOR slots
                const short* hp = (const short*)wb + lr * 64
                                  + (((tt * 4 + kg) ^ (lr & 7)) << 3);
                bf16x8 ar = *(const bf16x8*)hp;
                if (BN) {
                    const int kb = c * 64 + tt * 32 + kg * 8;
                    f32x4 c0 = *(const f32x4*)&bnl[kb];
                    f32x4 c1 = *(const f32x4*)&bnl[kb + 4];
                    f32x4 h0 = *(const f32x4*)&bnl[NCX * 64 + kb];
                    f32x4 h1 = *(const f32x4*)&bnl[NCX * 64 + kb + 4];
#pragma unroll
                    for (int e = 0; e < 4; ++e) {
                        a[e]     = f2bf(lrelu(fmaf(bf2f(ar[e]),     c0[e], h0[e])));
                        a[e + 4] = f2bf(lrelu(fmaf(bf2f(ar[e + 4]), c1[e], h1[e])));
                    }
                } else {
                    a = ar;
                }
            } else {
                // f32 fragment (skip region, or XMODE0 x region)
                const int p0 = tt * 4 + kg;
                const float* fp = wb + lr * 64 + ((p0 ^ (lr & 7)) << 3);
                f32x4 lo = *(const f32x4*)fp;
                f32x4 hi = *(const f32x4*)(fp + 4);
                float v[8];
#pragma unroll
                for (int e = 0; e < 4; ++e) { v[e] = lo[e]; v[e + 4] = hi[e]; }
#pragma unroll
                for (int e = 0; e < 8; ++e) a[e] = f2bf(v[e]);
            }
#pragma unroll
            for (int nt = 0; nt < NT; ++nt) {
                bf16x8 b;
                if constexpr (BMODE == 2)      b = Bp[(2 * c + tt) * NT + nt];
                else if constexpr (BMODE == 1) b = Bf[c % 3][tt][nt];
                else b = *(const bf16x8*)(wtf + (((2 * c + tt) * NT + nt) << 9));
                acc[nt] = __builtin_amdgcn_mfma_f32_16x16x32_bf16(a, b, acc[nt], 0, 0, 0);
            }
        }
    }

    // ---- bias + store ----
#pragma unroll
    for (int nt = 0; nt < NT; ++nt) {
        const int n = nt * 16 + lr;
        const float bv = (n < NVALID) ? bias[n] : 0.f;
#pragma unroll
        for (int r = 0; r < 4; ++r) acc[nt][r] += bv;
        if (n < NVALID) {
#pragma unroll
            for (int r = 0; r < 4; ++r) {
                const size_t o = (size_t)(row0w + kg * 4 + r) * ODe + n;
                if constexpr (OUTBF) ((short*)outv)[o] = f2bf(acc[nt][r]);
                else                 ((float*)outv)[o] = acc[nt][r];
            }
        }
    }

    // ---- stats: LDS accumulate, then 8-way-split global atomics ----
    if constexpr (STATS) {
        float* ls = &abuf[0][0][0];
        __syncthreads();
        for (int i = tid; i < 2 * NPAD; i += 256) ls[i] = 0.f;
        __syncthreads();
#pragma unroll
        for (int nt = 0; nt < NT; ++nt) {
            float s = acc[nt][0] + acc[nt][1] + acc[nt][2] + acc[nt][3];
            float q = acc[nt][0]*acc[nt][0] + acc[nt][1]*acc[nt][1]
                    + acc[nt][2]*acc[nt][2] + acc[nt][3]*acc[nt][3];
            s += __shfl_xor(s, 16, 64);
            s += __shfl_xor(s, 32, 64);
            q += __shfl_xor(q, 16, 64);
            q += __shfl_xor(q, 32, 64);
            if (lane < 16) {
                atomicAdd(&ls[nt * 16 + lr], s);
                atomicAdd(&ls[NPAD + nt * 16 + lr], q);
            }
        }
        __syncthreads();
        const int part = blockIdx.x & 7;
        for (int i = tid; i < NPAD; i += 256) {
            atomicAdd(&ssum[part * NPAD + i], ls[i]);
            atomicAdd(&ssq[part * NPAD + i], ls[NPAD + i]);
        }
    }
}

extern "C" void kernel_launch(void* const* d_in, const int* in_sizes, int n_in,
                              void* d_out, int out_size, void* d_ws, size_t ws_size,
                              hipStream_t stream) {
    const float* feats = (const float*)d_in[0];
    const float* skip1 = (const float*)d_in[1];
    const float* skip2 = (const float*)d_in[2];
    const float* skip3 = (const float*)d_in[3];
    const int*   idx1  = (const int*)d_in[4];
    const int*   idx2  = (const int*)d_in[5];
    const int*   idx3  = (const int*)d_in[6];
    const float* W1    = (const float*)d_in[7];
    const float* b1    = (const float*)d_in[8];
    const float* g1    = (const float*)d_in[9];
    const float* be1   = (const float*)d_in[10];
    const float* W2    = (const float*)d_in[11];
    const float* b2    = (const float*)d_in[12];
    const float* g2    = (const float*)d_in[13];
    const float* be2   = (const float*)d_in[14];
    const float* W3    = (const float*)d_in[15];
    const float* b3    = (const float*)d_in[16];

    float* ws   = (float*)d_ws;
    float* sum1 = ws;          // 8 x 144
    float* sq1  = ws + 1152;   // 8 x 144
    float* sum2 = ws + 2304;   // 8 x 64
    float* sq2  = ws + 2816;   // 8 x 64
    short* Wt1  = (short*)(ws + 4096);        // 26*9*512 = 119808
    short* Wt2  = Wt1 + 119808;               // 14*4*512 = 28672
    short* Wt3  = Wt2 + 28672;                // 6*3*512  = 9216
    short* y1h  = Wt3 + 9216;                 // [16384][192] bf16
    short* y2h  = y1h + (size_t)16384 * 192;  // [65536][64] bf16
    float* outp = (float*)d_out;

    prep<<<512, 256, 0, stream>>>(W1, W2, W3, Wt1, Wt2, Wt3, ws, y1h);

    // stage 1: feats f32 (gload4, clamp@258) + skip3(512), N=129 (NT=9),
    // B inline, out -> y1 bf16, stats 8-way
    mfma_stage<258, 512, 5, 8, 9, 129, 192, 0, 258, 0, 1, true, 0, 2, true>
        <<<256, 256, 0, stream>>>(feats, skip3, idx1, Wt1, b1,
                                  nullptr, nullptr, nullptr, nullptr, 0.f,
                                  y1h, sum1, sq1);

    // stage 2: y1 bf16 rows (XMODE2) + skip2(256), N=64, B triple-buffered,
    // BN1 finalized from 8 partials, out -> y2 bf16, stats 8-way
    mfma_stage<192, 256, 3, 4, 4, 64, 64, 2, 0, 129, 144, true, 1, 3, true>
        <<<1024, 256, 0, stream>>>(y1h, skip2, idx2, Wt2, b2,
                                   sum1, sq1, g1, be1, 1.f / 16384.f,
                                   y2h, sum2, sq2);

    // stage 3: y2 bf16 rows (XMODE2) + skip1(128), N=34, B fully preloaded,
    // BN2 finalized from 8 partials, out -> f32
    mfma_stage<64, 128, 1, 2, 3, 34, 34, 2, 0, 64, 64, false, 2, 3, false>
        <<<4096, 256, 0, stream>>>(y2h, skip1, idx3, Wt3, b3,
                                   sum2, sq2, g2, be2, 1.f / 65536.f,
                                   outp, nullptr, nullptr);
}